// Round 2
// baseline (631.329 us; speedup 1.0000x reference)
//
#include <hip/hip_runtime.h>
#include <hip/hip_bf16.h>
#include <stdint.h>

// LoRA linear: out = x @ W^T + b + 2*(x@A^T)@B^T, M=8192, N=K=4096, rank 16.
// Strategy: fold adapter into weights (W' = W + 2*B@A, bf16), single bf16 MFMA GEMM.
#define MM 8192
#define NN 4096
#define KK 4096
#define RANK 16
#define SCALING 2.0f

typedef __bf16 bf16x8 __attribute__((ext_vector_type(8)));
typedef float  f32x4  __attribute__((ext_vector_type(4)));

__device__ inline void async_copy16(const void* g, void* lds) {
    __builtin_amdgcn_global_load_lds(
        (const __attribute__((address_space(1))) void*)g,
        (__attribute__((address_space(3))) void*)lds,
        16, 0, 0);
}

// ---------------------------------------------------------------- fused pre-pass:
// blocks [0, 16384): x fp32 -> bf16 (8 elems/thread)
// blocks [16384, 24576): W' = W + 2*B@A -> bf16 (8 elems/thread)
#define CONV_BLOCKS 16384
#define PREP_BLOCKS 8192

__global__ void pre_kernel(const float* __restrict__ x,
                           const float* __restrict__ W,
                           const float* __restrict__ lA,
                           const float* __restrict__ lB,
                           __hip_bfloat16* __restrict__ xb,
                           __hip_bfloat16* __restrict__ wb) {
    int bid = blockIdx.x;
    if (bid < CONV_BLOCKS) {
        size_t i = (size_t)bid * 256 + threadIdx.x;      // one 8-elem chunk
        const float4* s = (const float4*)x + i * 2;
        float4 a = s[0], b = s[1];
        union { __hip_bfloat16 h[8]; uint4 u; } o;
        o.h[0] = __float2bfloat16(a.x); o.h[1] = __float2bfloat16(a.y);
        o.h[2] = __float2bfloat16(a.z); o.h[3] = __float2bfloat16(a.w);
        o.h[4] = __float2bfloat16(b.x); o.h[5] = __float2bfloat16(b.y);
        o.h[6] = __float2bfloat16(b.z); o.h[7] = __float2bfloat16(b.w);
        *((uint4*)xb + i) = o.u;
    } else {
        size_t idx = (size_t)(bid - CONV_BLOCKS) * 256 + threadIdx.x;
        int o  = (int)(idx >> 9);          // output row (KK/8 = 512 chunks/row)
        int i0 = ((int)idx & 511) << 3;
        const float4* wp = (const float4*)(W + (size_t)o * KK + i0);
        float4 w0 = wp[0], w1 = wp[1];
        float acc[8] = {0,0,0,0,0,0,0,0};
#pragma unroll
        for (int r = 0; r < RANK; ++r) {
            float bv = lB[o * RANK + r];
            const float4* ap = (const float4*)(lA + (size_t)r * KK + i0);
            float4 a0 = ap[0], a1 = ap[1];
            acc[0] += bv * a0.x; acc[1] += bv * a0.y;
            acc[2] += bv * a0.z; acc[3] += bv * a0.w;
            acc[4] += bv * a1.x; acc[5] += bv * a1.y;
            acc[6] += bv * a1.z; acc[7] += bv * a1.w;
        }
        float res[8] = { w0.x + SCALING * acc[0], w0.y + SCALING * acc[1],
                         w0.z + SCALING * acc[2], w0.w + SCALING * acc[3],
                         w1.x + SCALING * acc[4], w1.y + SCALING * acc[5],
                         w1.z + SCALING * acc[6], w1.w + SCALING * acc[7] };
        union { __hip_bfloat16 h[8]; uint4 u; } pk;
#pragma unroll
        for (int j = 0; j < 8; ++j) pk.h[j] = __float2bfloat16(res[j]);
        *((uint4*)wb + idx) = pk.u;
    }
}

// ---------------------------------------------------------------- main GEMM:
// C = A(bf16)@B(bf16)^T + bias. 128x128 tile, BK=32, 4 waves, 4x4 frags of
// mfma_f32_16x16x32_bf16. LDS chunk slots XOR-swizzled so fragment reads are
// 2-way-per-bank-group (free); swizzle applied on the GLOBAL source side since
// global_load_lds writes at fixed base+lane*16.
#define BM 128
#define BN 128
#define BK 32

__global__ __launch_bounds__(256, 4)
void gemm_bt_kernel(const __hip_bfloat16* __restrict__ A,
                    const __hip_bfloat16* __restrict__ B,
                    const float* __restrict__ bias,
                    float* __restrict__ C) {
    __shared__ __align__(16) __hip_bfloat16 As[BM * BK];  // 8 KiB
    __shared__ __align__(16) __hip_bfloat16 Bs[BN * BK];  // 8 KiB

    const int t     = threadIdx.x;
    const int lane  = t & 63;
    const int wave  = t >> 6;
    const int wm    = wave >> 1;
    const int wn    = wave & 1;
    const int row16 = lane & 15;
    const int quad  = lane >> 4;

    // XCD-aware tile mapping: 1D grid of 2048; id%8 = XCD (round-robin
    // heuristic). Each XCD sweeps a 16(bm) x 16(bn) region, bn-fast so 16
    // consecutive blocks on one XCD share an A stripe in its L2.
    const int id  = blockIdx.x;
    const int xcd = id & 7;
    const int lid = id >> 3;
    const int bm  = (xcd >> 1) * 16 + (lid >> 4);   // 0..63
    const int bn  = (xcd & 1) * 16 + (lid & 15);    // 0..31

    f32x4 acc[4][4] = {};

    // staging: thread t -> LDS row t>>2 (and +64), slot t&3.
    // slot s holds global chunk c = s ^ ((row>>1)&3)   (row period 8 <= 64 so
    // the +64-row copy uses the same swizzle).
    const int srow   = t >> 2;
    const int schunk = ((t & 3) ^ ((t >> 3) & 3)) * 8;
    const __hip_bfloat16* gA0 = A + (size_t)(bm * BM + srow) * KK + schunk;
    const __hip_bfloat16* gA1 = gA0 + (size_t)64 * KK;
    const __hip_bfloat16* gB0 = B + (size_t)(bn * BN + srow) * KK + schunk;
    const __hip_bfloat16* gB1 = gB0 + (size_t)64 * KK;

    char* ldsA = (char*)As + wave * 1024;
    char* ldsB = (char*)Bs + wave * 1024;

    // fragment-read slot: chunk quad lives at slot quad ^ ((row16>>1)&3)
    const int sw = (quad ^ ((row16 >> 1) & 3)) * 8;

    for (int kt = 0; kt < KK; kt += BK) {
        async_copy16(gA0 + kt, ldsA);
        async_copy16(gA1 + kt, ldsA + 4096);
        async_copy16(gB0 + kt, ldsB);
        async_copy16(gB1 + kt, ldsB + 4096);
        __syncthreads();

        bf16x8 af[4], bg[4];
#pragma unroll
        for (int mi = 0; mi < 4; ++mi)
            af[mi] = *(const bf16x8*)(As + (wm * 64 + mi * 16 + row16) * BK + sw);
#pragma unroll
        for (int ni = 0; ni < 4; ++ni)
            bg[ni] = *(const bf16x8*)(Bs + (wn * 64 + ni * 16 + row16) * BK + sw);
#pragma unroll
        for (int mi = 0; mi < 4; ++mi)
#pragma unroll
            for (int ni = 0; ni < 4; ++ni)
                acc[mi][ni] = __builtin_amdgcn_mfma_f32_16x16x32_bf16(
                    af[mi], bg[ni], acc[mi][ni], 0, 0, 0);
        __syncthreads();
    }

    // epilogue: C/D layout col=lane&15, row=quad*4+reg
    const int colBase = bn * BN + wn * 64;
    const int rowBase = bm * BM + wm * 64;
#pragma unroll
    for (int ni = 0; ni < 4; ++ni) {
        int col = colBase + ni * 16 + row16;
        float bv = bias[col];
#pragma unroll
        for (int mi = 0; mi < 4; ++mi) {
            int r0 = rowBase + mi * 16 + quad * 4;
#pragma unroll
            for (int i = 0; i < 4; ++i)
                C[(size_t)(r0 + i) * NN + col] = acc[mi][ni][i] + bv;
        }
    }
}

// ---------------------------------------------------------------- fallback (ws too small)
__global__ void naive_base_kernel(const float* __restrict__ x,
                                  const float* __restrict__ W,
                                  const float* __restrict__ b,
                                  float* __restrict__ out) {
    size_t idx = (size_t)blockIdx.x * 256 + threadIdx.x;
    int m = (int)(idx / NN), n = (int)(idx % NN);
    const float* xr = x + (size_t)m * KK;
    const float* wr = W + (size_t)n * KK;
    float s = 0.f;
    for (int k = 0; k < KK; ++k) s += xr[k] * wr[k];
    out[idx] = s + b[n];
}

__global__ void naive_adapter_kernel(const float* __restrict__ x,
                                     const float* __restrict__ lA,
                                     const float* __restrict__ lB,
                                     float* __restrict__ out) {
    int m = blockIdx.x;
    __shared__ float xa[RANK];
    __shared__ float red[256];
    const float* xr = x + (size_t)m * KK;
    for (int r = 0; r < RANK; ++r) {
        float p = 0.f;
        for (int k = threadIdx.x; k < KK; k += 256) p += xr[k] * lA[(size_t)r * KK + k];
        red[threadIdx.x] = p;
        __syncthreads();
        for (int s = 128; s > 0; s >>= 1) {
            if (threadIdx.x < s) red[threadIdx.x] += red[threadIdx.x + s];
            __syncthreads();
        }
        if (threadIdx.x == 0) xa[r] = red[0];
        __syncthreads();
    }
    for (int n = threadIdx.x; n < NN; n += 256) {
        float adj = 0.f;
#pragma unroll
        for (int r = 0; r < RANK; ++r) adj += xa[r] * lB[n * RANK + r];
        out[(size_t)m * NN + n] += SCALING * adj;
    }
}

// ---------------------------------------------------------------- launch
extern "C" void kernel_launch(void* const* d_in, const int* in_sizes, int n_in,
                              void* d_out, int out_size, void* d_ws, size_t ws_size,
                              hipStream_t stream) {
    const float* x  = (const float*)d_in[0];
    const float* W  = (const float*)d_in[1];
    const float* b  = (const float*)d_in[2];
    const float* lA = (const float*)d_in[3];
    const float* lB = (const float*)d_in[4];
    float* out = (float*)d_out;

    size_t need = (size_t)MM * KK * 2 + (size_t)NN * KK * 2;  // 96 MiB
    if (ws_size >= need) {
        __hip_bfloat16* xb = (__hip_bfloat16*)d_ws;
        __hip_bfloat16* wb = xb + (size_t)MM * KK;
        pre_kernel<<<CONV_BLOCKS + PREP_BLOCKS, 256, 0, stream>>>(x, W, lA, lB, xb, wb);
        gemm_bt_kernel<<<(MM / BM) * (NN / BN), 256, 0, stream>>>(xb, wb, b, out);
    } else {
        naive_base_kernel<<<(size_t)MM * NN / 256, 256, 0, stream>>>(x, W, b, out);
        naive_adapter_kernel<<<MM, 256, 0, stream>>>(x, lA, lB, out);
    }
}

// Round 3
// 565.074 us; speedup vs baseline: 1.1173x; 1.1173x over previous
//
#include <hip/hip_runtime.h>
#include <hip/hip_bf16.h>
#include <stdint.h>

// LoRA linear: out = x @ W^T + b + 2*(x@A^T)@B^T, M=8192, N=K=4096, rank 16.
// Strategy: fold adapter into weights (W' = W + 2*B@A, bf16), single bf16 MFMA GEMM.
#define MM 8192
#define NN 4096
#define KK 4096
#define RANK 16
#define SCALING 2.0f

typedef __bf16 bf16x8 __attribute__((ext_vector_type(8)));
typedef float  f32x4  __attribute__((ext_vector_type(4)));

__device__ inline void async_copy16(const void* g, void* lds) {
    __builtin_amdgcn_global_load_lds(
        (const __attribute__((address_space(1))) void*)g,
        (__attribute__((address_space(3))) void*)lds,
        16, 0, 0);
}

// ---------------------------------------------------------------- fused pre-pass:
// blocks [0, 16384): x fp32 -> bf16 (8 elems/thread)
// blocks [16384, 24576): W' = W + 2*B@A -> bf16 (8 elems/thread)
#define CONV_BLOCKS 16384
#define PREP_BLOCKS 8192

__global__ void pre_kernel(const float* __restrict__ x,
                           const float* __restrict__ W,
                           const float* __restrict__ lA,
                           const float* __restrict__ lB,
                           __hip_bfloat16* __restrict__ xb,
                           __hip_bfloat16* __restrict__ wb) {
    int bid = blockIdx.x;
    if (bid < CONV_BLOCKS) {
        size_t i = (size_t)bid * 256 + threadIdx.x;      // one 8-elem chunk
        const float4* s = (const float4*)x + i * 2;
        float4 a = s[0], b = s[1];
        union { __hip_bfloat16 h[8]; uint4 u; } o;
        o.h[0] = __float2bfloat16(a.x); o.h[1] = __float2bfloat16(a.y);
        o.h[2] = __float2bfloat16(a.z); o.h[3] = __float2bfloat16(a.w);
        o.h[4] = __float2bfloat16(b.x); o.h[5] = __float2bfloat16(b.y);
        o.h[6] = __float2bfloat16(b.z); o.h[7] = __float2bfloat16(b.w);
        *((uint4*)xb + i) = o.u;
    } else {
        size_t idx = (size_t)(bid - CONV_BLOCKS) * 256 + threadIdx.x;
        int o  = (int)(idx >> 9);          // output row (KK/8 = 512 chunks/row)
        int i0 = ((int)idx & 511) << 3;
        const float4* wp = (const float4*)(W + (size_t)o * KK + i0);
        float4 w0 = wp[0], w1 = wp[1];
        float acc[8] = {0,0,0,0,0,0,0,0};
#pragma unroll
        for (int r = 0; r < RANK; ++r) {
            float bv = lB[o * RANK + r];
            const float4* ap = (const float4*)(lA + (size_t)r * KK + i0);
            float4 a0 = ap[0], a1 = ap[1];
            acc[0] += bv * a0.x; acc[1] += bv * a0.y;
            acc[2] += bv * a0.z; acc[3] += bv * a0.w;
            acc[4] += bv * a1.x; acc[5] += bv * a1.y;
            acc[6] += bv * a1.z; acc[7] += bv * a1.w;
        }
        float res[8] = { w0.x + SCALING * acc[0], w0.y + SCALING * acc[1],
                         w0.z + SCALING * acc[2], w0.w + SCALING * acc[3],
                         w1.x + SCALING * acc[4], w1.y + SCALING * acc[5],
                         w1.z + SCALING * acc[6], w1.w + SCALING * acc[7] };
        union { __hip_bfloat16 h[8]; uint4 u; } pk;
#pragma unroll
        for (int j = 0; j < 8; ++j) pk.h[j] = __float2bfloat16(res[j]);
        *((uint4*)wb + idx) = pk.u;
    }
}

// ---------------------------------------------------------------- main GEMM:
// C = A(bf16)@B(bf16)^T + bias. 128x128 tile, BK=64 (32 MFMA per barrier pair
// — AITER granularity), 4 waves, 4x4 frags of mfma_f32_16x16x32_bf16.
// LDS: row-major [128][64] bf16 per matrix (row stride 128 B). 16-B chunk
// slots XOR-swizzled (slot = chunk ^ (row&7)) on the GLOBAL source side so
// fragment ds_read_b128s are 2-way-per-bank (free, m136) — global_load_lds
// writes at fixed base+lane*16 so the permutation must ride on the source.
#define BM 128
#define BN 128
#define BK 64

__global__ __launch_bounds__(256, 3)
void gemm_bt_kernel(const __hip_bfloat16* __restrict__ A,
                    const __hip_bfloat16* __restrict__ B,
                    const float* __restrict__ bias,
                    float* __restrict__ C) {
    __shared__ __align__(16) __hip_bfloat16 As[BM * BK];  // 16 KiB
    __shared__ __align__(16) __hip_bfloat16 Bs[BN * BK];  // 16 KiB

    const int t     = threadIdx.x;
    const int lane  = t & 63;
    const int wave  = t >> 6;
    const int wm    = wave >> 1;
    const int wn    = wave & 1;
    const int row16 = lane & 15;
    const int quad  = lane >> 4;
    const int bm = blockIdx.y, bn = blockIdx.x;   // 2D grid, x-fast (R1 mapping)

    f32x4 acc[4][4] = {};

    // staging: thread t -> row t>>3 (+32 per sweep), slot t&7.
    // slot s at row r holds global chunk c = s ^ (r & 7); row period 8 divides
    // the 32-row sweep stride so all 4 sweeps share the thread's swizzle.
    const int srow   = t >> 3;                       // 0..31
    const int schunk = ((t & 7) ^ ((t >> 3) & 7)) * 8;
    const __hip_bfloat16* gA = A + (size_t)(bm * BM + srow) * KK + schunk;
    const __hip_bfloat16* gB = B + (size_t)(bn * BN + srow) * KK + schunk;

    // wave-uniform LDS bases (HW writes base + lane*16); sweep s adds 32 rows
    char* ldsA = (char*)As + wave * 1024;
    char* ldsB = (char*)Bs + wave * 1024;

    for (int kt = 0; kt < KK; kt += BK) {
#pragma unroll
        for (int s = 0; s < 4; ++s) {
            async_copy16(gA + (size_t)(32 * s) * KK + kt, ldsA + s * 4096);
            async_copy16(gB + (size_t)(32 * s) * KK + kt, ldsB + s * 4096);
        }
        __syncthreads();   // drain: tile resident in LDS

#pragma unroll
        for (int h = 0; h < 2; ++h) {      // K halves: k0 = 32*h
            bf16x8 af[4], bg[4];
            const int cbase = 4 * h + quad;             // chunk index 0..7
            const int slot  = (cbase ^ (row16 & 7)) * 8; // element offset in row
#pragma unroll
            for (int mi = 0; mi < 4; ++mi)
                af[mi] = *(const bf16x8*)(As + (wm * 64 + mi * 16 + row16) * BK + slot);
#pragma unroll
            for (int ni = 0; ni < 4; ++ni)
                bg[ni] = *(const bf16x8*)(Bs + (wn * 64 + ni * 16 + row16) * BK + slot);
#pragma unroll
            for (int mi = 0; mi < 4; ++mi)
#pragma unroll
                for (int ni = 0; ni < 4; ++ni)
                    acc[mi][ni] = __builtin_amdgcn_mfma_f32_16x16x32_bf16(
                        af[mi], bg[ni], acc[mi][ni], 0, 0, 0);
        }
        __syncthreads();   // before next iteration overwrites LDS
    }

    // epilogue: C/D layout col=lane&15, row=quad*4+reg
    const int colBase = bn * BN + wn * 64;
    const int rowBase = bm * BM + wm * 64;
#pragma unroll
    for (int ni = 0; ni < 4; ++ni) {
        int col = colBase + ni * 16 + row16;
        float bv = bias[col];
#pragma unroll
        for (int mi = 0; mi < 4; ++mi) {
            int r0 = rowBase + mi * 16 + quad * 4;
#pragma unroll
            for (int i = 0; i < 4; ++i)
                C[(size_t)(r0 + i) * NN + col] = acc[mi][ni][i] + bv;
        }
    }
}

// ---------------------------------------------------------------- fallback (ws too small)
__global__ void naive_base_kernel(const float* __restrict__ x,
                                  const float* __restrict__ W,
                                  const float* __restrict__ b,
                                  float* __restrict__ out) {
    size_t idx = (size_t)blockIdx.x * 256 + threadIdx.x;
    int m = (int)(idx / NN), n = (int)(idx % NN);
    const float* xr = x + (size_t)m * KK;
    const float* wr = W + (size_t)n * KK;
    float s = 0.f;
    for (int k = 0; k < KK; ++k) s += xr[k] * wr[k];
    out[idx] = s + b[n];
}

__global__ void naive_adapter_kernel(const float* __restrict__ x,
                                     const float* __restrict__ lA,
                                     const float* __restrict__ lB,
                                     float* __restrict__ out) {
    int m = blockIdx.x;
    __shared__ float xa[RANK];
    __shared__ float red[256];
    const float* xr = x + (size_t)m * KK;
    for (int r = 0; r < RANK; ++r) {
        float p = 0.f;
        for (int k = threadIdx.x; k < KK; k += 256) p += xr[k] * lA[(size_t)r * KK + k];
        red[threadIdx.x] = p;
        __syncthreads();
        for (int s = 128; s > 0; s >>= 1) {
            if (threadIdx.x < s) red[threadIdx.x] += red[threadIdx.x + s];
            __syncthreads();
        }
        if (threadIdx.x == 0) xa[r] = red[0];
        __syncthreads();
    }
    for (int n = threadIdx.x; n < NN; n += 256) {
        float adj = 0.f;
#pragma unroll
        for (int r = 0; r < RANK; ++r) adj += xa[r] * lB[n * RANK + r];
        out[(size_t)m * NN + n] += SCALING * adj;
    }
}

// ---------------------------------------------------------------- launch
extern "C" void kernel_launch(void* const* d_in, const int* in_sizes, int n_in,
                              void* d_out, int out_size, void* d_ws, size_t ws_size,
                              hipStream_t stream) {
    const float* x  = (const float*)d_in[0];
    const float* W  = (const float*)d_in[1];
    const float* b  = (const float*)d_in[2];
    const float* lA = (const float*)d_in[3];
    const float* lB = (const float*)d_in[4];
    float* out = (float*)d_out;

    size_t need = (size_t)MM * KK * 2 + (size_t)NN * KK * 2;  // 96 MiB
    if (ws_size >= need) {
        __hip_bfloat16* xb = (__hip_bfloat16*)d_ws;
        __hip_bfloat16* wb = xb + (size_t)MM * KK;
        pre_kernel<<<CONV_BLOCKS + PREP_BLOCKS, 256, 0, stream>>>(x, W, lA, lB, xb, wb);
        gemm_bt_kernel<<<dim3(NN / BN, MM / BM), 256, 0, stream>>>(xb, wb, b, out);
    } else {
        naive_base_kernel<<<(size_t)MM * NN / 256, 256, 0, stream>>>(x, W, b, out);
        naive_adapter_kernel<<<MM, 256, 0, stream>>>(x, lA, lB, out);
    }
}